// Round 2
// baseline (321.593 us; speedup 1.0000x reference)
//
#include <hip/hip_runtime.h>
#include <hip/hip_bf16.h>
#include <math.h>

// Problem constants (fixed by reference)
constexpr int BB = 4;
constexpr int LL = 2048;
constexpr int EE = 512;
constexpr int HH = 8;
constexpr int DD = 64;
constexpr int UU = 40;    // sample count
constexpr int NT = 40;    // n_top
constexpr int NCH = 32;   // key chunks (64 keys each) for split-K attention
constexpr int CK = 64;    // keys per chunk
constexpr int MVC = 16;   // L-chunks for meanv stage 1 (128 rows each)
constexpr float NEG_INF = -3.0e38f;

typedef __attribute__((ext_vector_type(8))) short bf8_t;  // 8 bf16 (4 VGPR)
typedef __attribute__((ext_vector_type(4))) float f4_t;   // MFMA C/D frag

// ---------------------------------------------------------------------------
// split helpers: f32 = hi(RNE bf16) + mid(trunc bf16). Bit-identical math to
// the previous rounds (absmax must stay at 2.44e-4).
// ---------------------------------------------------------------------------
__device__ __forceinline__ void split2pair(float x0, float x1, uint& hp, uint& mp)
{
    uint xb0 = __float_as_uint(x0), xb1 = __float_as_uint(x1);
    uint hb0 = xb0 + 0x7fffu + ((xb0 >> 16) & 1u);
    uint hb1 = xb1 + 0x7fffu + ((xb1 >> 16) & 1u);
    hp = __builtin_amdgcn_perm(hb1, hb0, 0x07060302u);            // [h1.hi16|h0.hi16]
    float r0 = x0 - __uint_as_float(hb0 & 0xffff0000u);
    float r1 = x1 - __uint_as_float(hb1 & 0xffff0000u);
    mp = __builtin_amdgcn_perm(__float_as_uint(r1), __float_as_uint(r0), 0x07060302u);
}

__device__ __forceinline__ void gload16(const void* g, void* l)
{
    __builtin_amdgcn_global_load_lds(
        (const __attribute__((address_space(1))) unsigned int*)g,
        (__attribute__((address_space(3))) unsigned int*)l, 16, 0, 0);
}

__device__ __forceinline__ int swz(int row, int c)
{
    return row * 64 + (((c ^ row ^ (row >> 2)) & 3) << 4);
}

// ---------------------------------------------------------------------------
// K0: pre-convert Wq/Wk/Wv (f32 [512][512]) to bf16 hi+mid planes.
// Output layout wcv[z][plane][512*512] ushort, z in {q,k,v}, plane in {hi,mid}.
// ---------------------------------------------------------------------------
__global__ __launch_bounds__(256) void wconv_kernel(
    const float* __restrict__ Wq, const float* __restrict__ Wk,
    const float* __restrict__ Wv, unsigned short* __restrict__ wcv)
{
    const int gi  = blockIdx.x * 256 + threadIdx.x;   // 0..98303
    const int z   = gi >> 15;                         // 32768 threads per matrix
    const int off = (gi & 32767) * 8;
    const float* W = (z == 0) ? Wq : (z == 1 ? Wk : Wv);
    float x[8];
    *(float4*)(x)     = *(const float4*)(W + off);
    *(float4*)(x + 4) = *(const float4*)(W + off + 4);
    uint hp[4], mp[4];
#pragma unroll
    for (int p = 0; p < 4; p++) split2pair(x[2 * p], x[2 * p + 1], hp[p], mp[p]);
    unsigned short* Wh = wcv + (size_t)z * 524288;
    *(uint4*)(Wh + off)          = make_uint4(hp[0], hp[1], hp[2], hp[3]);
    *(uint4*)(Wh + 262144 + off) = make_uint4(mp[0], mp[1], mp[2], mp[3]);
}

// ---------------------------------------------------------------------------
// K1: fused QKV projection. 128x128x32 tile, 4 waves, 3-product split-bf16
// MFMA. This revision: single-barrier pipelined K-loop.
//  - A AND B double-buffered (LDS 64KB -> 2 blocks/CU). One raw s_barrier per
//    K-step with a COUNTED s_waitcnt vmcnt(4): the 4 outstanding ops allowed
//    across the barrier are exactly the fa(i+2) global loads, so the deep
//    prefetch survives the barrier (T3/T4 pattern). B(i+1) gload_lds are
//    issued BEFORE the fa loads (empty asm memory fence enforces order;
//    vmcnt retires in-order, so vmcnt(4) == B complete).
//  - Dataflow: iter i reads bufs [i&1]; converts fa(i+1)->A-buf[(i+1)&1];
//    issues B(i+1)->B-buf[(i+1)&1]; issues fa(i+2)->regs. Every load gets a
//    full iteration (~700cy) of latency cover instead of ~300-500cy.
//  - Race audit: all writes target buf p^1 whose last readers finished before
//    the preceding barrier (each wave does lgkmcnt(0) pre-barrier). MFMA/
//    ds_read hazards are compiler-tracked (no inline-asm ds_reads).
// ---------------------------------------------------------------------------
__global__ __launch_bounds__(256, 2) void proj_kernel(
    const float* __restrict__ Xq, const float* __restrict__ Xk, const float* __restrict__ Xv,
    const unsigned short* __restrict__ Wcv,
    const float* __restrict__ bq, const float* __restrict__ bk, const float* __restrict__ bv,
    float* __restrict__ Oq, float* __restrict__ Ok, float* __restrict__ Ov)
{
    // XCD-grouped decode: 768 = 8 xcd * 96; same (yi,zi) -> same xcd.
    const int bid = blockIdx.x;
    const int xg  = bid & 7;
    const int s   = bid >> 3;            // 0..95
    const int yz  = xg * 24 + (s >> 2);  // 0..191
    const int zi  = yz >> 6;             // 0..2
    const int yi  = yz & 63;
    const int m0  = yi * 128;
    const int n0  = (s & 3) * 128;

    const float* X; const float* bias; float* O;
    if (zi == 0)      { X = Xq; bias = bq; O = Oq; }
    else if (zi == 1) { X = Xk; bias = bk; O = Ok; }
    else              { X = Xv; bias = bv; O = Ov; }
    const unsigned short* Wh = Wcv + (size_t)zi * 524288;
    const unsigned short* Wm = Wh + 262144;

    __shared__ char ldsmem[65536];
    char* const LA  = ldsmem;            // A bufs: [p]<<14; hi@0 mid@8192
    char* const LBt = ldsmem + 32768;    // B bufs: [p]<<14; hi@0 mid@8192

    const int tid  = threadIdx.x;
    const int lane = tid & 63;
    const int wave = tid >> 6;

    // A staging (reg-staged: on-the-fly split): thread covers row tid>>1,
    // 16 f32 at half (tid&1); swizzled LDS writes.
    const int srow  = tid >> 1;
    const int shalf = tid & 1;
    const int w0 = swz(srow, shalf * 2);
    const int w1 = swz(srow, shalf * 2 + 1);
    const float* Aptr = X + (size_t)(m0 + srow) * EE + shalf * 16;

    // B staging via global_load_lds: linear dest, inverse-swizzled SOURCE.
    const int r0 = tid >> 2;
    const int r1 = 64 + r0;
    const int c0 = (tid & 3) ^ ((r0 ^ (r0 >> 2)) & 3);
    const int c1 = (tid & 3) ^ ((r1 ^ (r1 >> 2)) & 3);
    const unsigned short* bh0 = Wh + (size_t)(n0 + r0) * EE + c0 * 8;
    const unsigned short* bh1 = Wh + (size_t)(n0 + r1) * EE + c1 * 8;
    const unsigned short* bm0 = Wm + (size_t)(n0 + r0) * EE + c0 * 8;
    const unsigned short* bm1 = Wm + (size_t)(n0 + r1) * EE + c1 * 8;
    const int ldst = tid * 16;           // linear dest: wave-uniform base + lane*16

    const int rxor = ((((lane >> 4) ^ lane ^ (lane >> 2)) & 3) << 4);
    const int arow = (wave >> 1) * 64 + (lane & 15);
    const int brow = (wave & 1) * 64 + (lane & 15);

    f4_t acc[4][4];
#pragma unroll
    for (int i = 0; i < 4; i++)
#pragma unroll
        for (int j = 0; j < 4; j++) acc[i][j] = (f4_t)0.0f;

    float faA[16], faB[16];

    // ---- prologue: A(0) -> Abuf0, B(0) gloads -> Bbuf0, fa(1) -> faB ----
    {
        float f0[16];
#pragma unroll
        for (int q = 0; q < 4; q++)
            *(float4*)(f0 + q * 4) = *(const float4*)(Aptr + q * 4);
        uint ahu[8], amu[8];
#pragma unroll
        for (int p = 0; p < 8; p++)
            split2pair(f0[2 * p], f0[2 * p + 1], ahu[p], amu[p]);
        *(uint4*)(LA +    0 + w0) = make_uint4(ahu[0], ahu[1], ahu[2], ahu[3]);
        *(uint4*)(LA +    0 + w1) = make_uint4(ahu[4], ahu[5], ahu[6], ahu[7]);
        *(uint4*)(LA + 8192 + w0) = make_uint4(amu[0], amu[1], amu[2], amu[3]);
        *(uint4*)(LA + 8192 + w1) = make_uint4(amu[4], amu[5], amu[6], amu[7]);
        gload16(bh0, LBt + ldst);
        gload16(bh1, LBt + 4096 + ldst);
        gload16(bm0, LBt + 8192 + ldst);
        gload16(bm1, LBt + 12288 + ldst);
        asm volatile("" ::: "memory");   // keep B gloads older than fa loads
#pragma unroll
        for (int q = 0; q < 4; q++)
            *(float4*)(faB + q * 4) = *(const float4*)(Aptr + 32 + q * 4);
        asm volatile("s_waitcnt vmcnt(4) lgkmcnt(0)" ::: "memory");  // B(0) done
        __builtin_amdgcn_s_barrier();
    }

    // ---- main loop: one barrier per K-step ----
    auto body = [&](int i, float* fconv, float* fload) {
        char* const Ab = LA  + ((i & 1) << 14);
        char* const Bb = LBt + ((i & 1) << 14);

        // A fragments for this step
        bf8_t af[4][2];
#pragma unroll
        for (int i4 = 0; i4 < 4; i4++) {
            const int ro = (arow + i4 * 16) * 64 + rxor;
            af[i4][0] = *(const bf8_t*)(Ab +    0 + ro);
            af[i4][1] = *(const bf8_t*)(Ab + 8192 + ro);
        }

        if (i < 15) {
            // convert fa(i+1) and write A(i+1) into the other buffer
            uint ahu[8], amu[8];
#pragma unroll
            for (int p = 0; p < 8; p++)
                split2pair(fconv[2 * p], fconv[2 * p + 1], ahu[p], amu[p]);
            char* const Aw = LA + (((i + 1) & 1) << 14);
            *(uint4*)(Aw +    0 + w0) = make_uint4(ahu[0], ahu[1], ahu[2], ahu[3]);
            *(uint4*)(Aw +    0 + w1) = make_uint4(ahu[4], ahu[5], ahu[6], ahu[7]);
            *(uint4*)(Aw + 8192 + w0) = make_uint4(amu[0], amu[1], amu[2], amu[3]);
            *(uint4*)(Aw + 8192 + w1) = make_uint4(amu[4], amu[5], amu[6], amu[7]);
            // issue B(i+1) gloads into the other buffer
            const int kn = (i + 1) * 32;
            char* const Bw = LBt + (((i + 1) & 1) << 14);
            gload16(bh0 + kn, Bw + ldst);
            gload16(bh1 + kn, Bw + 4096 + ldst);
            gload16(bm0 + kn, Bw + 8192 + ldst);
            gload16(bm1 + kn, Bw + 12288 + ldst);
        }
        asm volatile("" ::: "memory");   // B gloads must stay older than fa loads
        if (i < 14) {
            const int kf = (i + 2) * 32;
#pragma unroll
            for (int q = 0; q < 4; q++)
                *(float4*)(fload + q * 4) = *(const float4*)(Aptr + kf + q * 4);
        }

        // MFMA over this step's B fragments
#pragma unroll
        for (int j = 0; j < 4; j++) {
            const int ro = (brow + j * 16) * 64 + rxor;
            bf8_t bh_ = *(const bf8_t*)(Bb +    0 + ro);
            bf8_t bm_ = *(const bf8_t*)(Bb + 8192 + ro);
#pragma unroll
            for (int i4 = 0; i4 < 4; i4++) {
                f4_t c = acc[i4][j];
                c = __builtin_amdgcn_mfma_f32_16x16x32_bf16(af[i4][0], bh_, c, 0, 0, 0); // hh
                c = __builtin_amdgcn_mfma_f32_16x16x32_bf16(af[i4][0], bm_, c, 0, 0, 0); // hm
                c = __builtin_amdgcn_mfma_f32_16x16x32_bf16(af[i4][1], bh_, c, 0, 0, 0); // mh
                acc[i4][j] = c;
            }
        }

        if (i < 15) {
            if (i < 14)
                asm volatile("s_waitcnt vmcnt(4) lgkmcnt(0)" ::: "memory"); // B(i+1) done; fa(i+2) in flight
            else
                asm volatile("s_waitcnt vmcnt(0) lgkmcnt(0)" ::: "memory"); // last: drain all
            __builtin_amdgcn_s_barrier();
        }
    };

    for (int it = 0; it < 16; it += 2) {
        body(it,     faB, faA);
        body(it + 1, faA, faB);
    }

    // ---- epilogue: C write ----
#pragma unroll
    for (int j = 0; j < 4; j++) {
        const int n  = n0 + (wave & 1) * 64 + j * 16 + (lane & 15);
        const float bn = bias[n];
        const int h_ = n >> 6, d_ = n & 63;
#pragma unroll
        for (int i = 0; i < 4; i++) {
            const int mb = m0 + (wave >> 1) * 64 + i * 16 + ((lane >> 4) << 2);
#pragma unroll
            for (int r = 0; r < 4; r++) {
                const int m  = mb + r;
                const int b_ = m >> 11;
                const int l_ = m & (LL - 1);
                O[(((size_t)(b_ * HH + h_) * LL + l_) << 6) + d_] = acc[i][j][r] + bn;
            }
        }
    }
}

// ---------------------------------------------------------------------------
// K2a: mean of V stage 1 — 512 blocks = (lchunk 0..15) x (bh 0..31).
// ---------------------------------------------------------------------------
__global__ __launch_bounds__(256) void meanv_part_kernel(const float* __restrict__ v,
                                                         float* __restrict__ vpart)
{
    const int bh    = blockIdx.x & 31;
    const int chunk = blockIdx.x >> 5;
    const int d  = threadIdx.x & 63;
    const int wv = threadIdx.x >> 6;
    const float* base = v + ((size_t)bh * LL + chunk * 128 + wv * 32) * DD + d;
    float acc = 0.0f;
#pragma unroll
    for (int i = 0; i < 32; i++) acc += base[i * DD];
    __shared__ float red[4][DD];
    red[wv][d] = acc;
    __syncthreads();
    if (wv == 0)
        vpart[(size_t)(chunk * 32 + bh) * DD + d]
            = red[0][d] + red[1][d] + red[2][d] + red[3][d];
}

// ---------------------------------------------------------------------------
// K2b: mean of V stage 2 — combine 16 partials per (bh,d).
// ---------------------------------------------------------------------------
__global__ __launch_bounds__(64) void meanv_comb_kernel(const float* __restrict__ vpart,
                                                        float* __restrict__ mean_v)
{
    const int bh = blockIdx.x;
    const int d  = threadIdx.x;
    float s = 0.0f;
#pragma unroll
    for (int c = 0; c < MVC; c++) s += vpart[(size_t)(c * 32 + bh) * DD + d];
    mean_v[bh * DD + d] = s * (1.0f / (float)LL);
}

// ---------------------------------------------------------------------------
// K3: sparsity measure M[b,h,l] = max_s(q.k_sample) - sum_s(q.k_sample)/L
// One wave per (b,h,l). Lane map: 8 samples x 8 d-chunks.
// ---------------------------------------------------------------------------
__global__ __launch_bounds__(256) void measure_kernel(const float* __restrict__ q,
                                                      const float* __restrict__ k,
                                                      const int* __restrict__ idx_sample,
                                                      float* __restrict__ M)
{
    int bh   = blockIdx.x & 31;
    int lc   = blockIdx.x >> 5;
    int lane = threadIdx.x & 63;
    int wv   = threadIdx.x >> 6;
    int l    = lc * 4 + wv;
    int s8   = lane >> 3;   // sample slot 0..7
    int c    = lane & 7;    // d-chunk 0..7

    const float* qrow = q + ((size_t)bh * LL + l) * DD + c * 8;
    float4 q0 = *(const float4*)(qrow);
    float4 q1 = *(const float4*)(qrow + 4);

    const float* kbase = k + (size_t)bh * LL * DD;
    const int*   irow  = idx_sample + l * UU;

    float mx = NEG_INF, sum = 0.0f;
#pragma unroll
    for (int it = 0; it < UU; it += 8) {
        int ki = irow[it + s8];
        const float* krow = kbase + (size_t)ki * DD + c * 8;
        float4 k0 = *(const float4*)(krow);
        float4 k1 = *(const float4*)(krow + 4);
        float p = q0.x*k0.x + q0.y*k0.y + q0.z*k0.z + q0.w*k0.w
                + q1.x*k1.x + q1.y*k1.y + q1.z*k1.z + q1.w*k1.w;
        p += __shfl_xor(p, 1, 64);
        p += __shfl_xor(p, 2, 64);
        p += __shfl_xor(p, 4, 64);
        mx = fmaxf(mx, p);
        sum += p;
    }
    mx  = fmaxf(mx, __shfl_xor(mx, 8, 64));
    sum += __shfl_xor(sum, 8, 64);
    mx  = fmaxf(mx, __shfl_xor(mx, 16, 64));
    sum += __shfl_xor(sum, 16, 64);
    mx  = fmaxf(mx, __shfl_xor(mx, 32, 64));
    sum += __shfl_xor(sum, 32, 64);

    if (lane == 0) M[bh * LL + l] = mx - sum * (1.0f / (float)LL);
}

// ---------------------------------------------------------------------------
// K4: top-40 per (b,h), single-wave register version.
// ---------------------------------------------------------------------------
__global__ __launch_bounds__(64) void topk_kernel(const float* __restrict__ M,
                                                  int* __restrict__ top)
{
    const int bh   = blockIdx.x;
    const int lane = threadIdx.x;

    unsigned long long keys[32];
#pragma unroll
    for (int i = 0; i < 32; i++) {
        int idx = i * 64 + lane;
        uint u  = __float_as_uint(M[bh * LL + idx]);
        uint sv = (u & 0x80000000u) ? ~u : (u | 0x80000000u);
        keys[i] = ((unsigned long long)sv << 32) | (uint)(LL - 1 - idx);
    }
    unsigned long long lmax = 0ull;
#pragma unroll
    for (int i = 0; i < 32; i++) lmax = (keys[i] > lmax) ? keys[i] : lmax;

    for (int it = 0; it < NT; it++) {
        unsigned long long g = lmax;
#pragma unroll
        for (int off = 1; off < 64; off <<= 1) {
            unsigned long long o = __shfl_xor(g, off, 64);
            g = (o > g) ? o : g;
        }
        if (lane == 0) top[bh * NT + it] = LL - 1 - (int)(g & 0xffffffffu);
#pragma unroll
        for (int i = 0; i < 32; i++) if (keys[i] == g) keys[i] = 0ull;
        lmax = 0ull;
#pragma unroll
        for (int i = 0; i < 32; i++) lmax = (keys[i] > lmax) ? keys[i] : lmax;
    }
}

// ---------------------------------------------------------------------------
// K5: flash-style split-K attention partials.
// ---------------------------------------------------------------------------
__global__ __launch_bounds__(256) void pv_kernel(const float* __restrict__ q,
                                                 const float* __restrict__ k,
                                                 const float* __restrict__ v,
                                                 const int* __restrict__ top,
                                                 float* __restrict__ mpart,
                                                 float* __restrict__ lpart,
                                                 float* __restrict__ accpart)
{
    const int bh    = blockIdx.x & 31;
    const int chunk = blockIdx.x >> 5;
    const int tid   = threadIdx.x;
    const int lane  = tid & 63, wv = tid >> 6;

    __shared__ alignas(16) float qs[NT][DD];        // 10240 B
    __shared__ alignas(16) float sc[NT][CK + 4];    // 10880 B (stride 272B, 16-mult)

    for (int i = tid; i < NT * DD / 4; i += 256) {
        int u  = i >> 4;
        int d4 = (i & 15) * 4;
        int l  = top[bh * NT + u];
        *(float4*)&qs[u][d4] = *(const float4*)(q + ((size_t)bh * LL + l) * DD + d4);
    }
    __syncthreads();

    {
        const int key  = tid >> 2;
        const int dseg = tid & 3;
        const float* krow = k + ((size_t)bh * LL + chunk * CK + key) * DD + dseg * 16;
        float4 k0 = *(const float4*)(krow);
        float4 k1 = *(const float4*)(krow + 4);
        float4 k2 = *(const float4*)(krow + 8);
        float4 k3 = *(const float4*)(krow + 12);
#pragma unroll 8
        for (int u = 0; u < NT; u++) {
            const float* qrow = &qs[u][dseg * 16];
            float4 q0 = *(const float4*)(qrow);
            float4 q1 = *(const float4*)(qrow + 4);
            float4 q2 = *(const float4*)(qrow + 8);
            float4 q3 = *(const float4*)(qrow + 12);
            float p = k0.x*q0.x + k0.y*q0.y + k0.z*q0.z + k0.w*q0.w
                    + k1.x*q1.x + k1.y*q1.y + k1.z*q1.z + k1.w*q1.w
                    + k2.x*q2.x + k2.y*q2.y + k2.z*q2.z + k2.w*q2.w
                    + k3.x*q3.x + k3.y*q3.y + k3.z*q3.z + k3.w*q3.w;
            p += __shfl_xor(p, 1, 64);
            p += __shfl_xor(p, 2, 64);
            if (dseg == 0) sc[u][key] = p;
        }
    }
    __syncthreads();

#pragma unroll
    for (int i = 0; i < 10; i++) {
        const int u = wv * 10 + i;
        float val = sc[u][lane];
        float mx = val;
        mx = fmaxf(mx, __shfl_xor(mx, 1, 64));
        mx = fmaxf(mx, __shfl_xor(mx, 2, 64));
        mx = fmaxf(mx, __shfl_xor(mx, 4, 64));
        mx = fmaxf(mx, __shfl_xor(mx, 8, 64));
        mx = fmaxf(mx, __shfl_xor(mx, 16, 64));
        mx = fmaxf(mx, __shfl_xor(mx, 32, 64));
        float e = __expf(val - mx);
        sc[u][lane] = e;
        float s = e;
        s += __shfl_xor(s, 1, 64);
        s += __shfl_xor(s, 2, 64);
        s += __shfl_xor(s, 4, 64);
        s += __shfl_xor(s, 8, 64);
        s += __shfl_xor(s, 16, 64);
        s += __shfl_xor(s, 32, 64);
        if (lane == 0) {
            mpart[(bh * NCH + chunk) * NT + u] = mx;
            lpart[(bh * NCH + chunk) * NT + u] = s;
        }
    }
    __syncthreads();

    {
        float pacc[10];
#pragma unroll
        for (int i = 0; i < 10; i++) pacc[i] = 0.0f;
        const float* vbase = v + ((size_t)bh * LL + chunk * CK) * DD + lane;
#pragma unroll 4
        for (int t = 0; t < CK; t += 4) {
            float v0 = vbase[(size_t)(t + 0) * DD];
            float v1 = vbase[(size_t)(t + 1) * DD];
            float v2 = vbase[(size_t)(t + 2) * DD];
            float v3 = vbase[(size_t)(t + 3) * DD];
#pragma unroll
            for (int i = 0; i < 10; i++) {
                float4 s = *(const float4*)&sc[wv * 10 + i][t];
                pacc[i] += s.x * v0 + s.y * v1 + s.z * v2 + s.w * v3;
            }
        }
#pragma unroll
        for (int i = 0; i < 10; i++) {
            const int u = wv * 10 + i;
            accpart[(((size_t)(bh * NCH + chunk)) * NT + u) * 64 + lane] = pacc[i];
        }
    }
}

// ---------------------------------------------------------------------------
// K6a: base output row per batch: base[b,e] = meanctx[b,:] . Wo[e,:] + bo[e]
// ---------------------------------------------------------------------------
__global__ __launch_bounds__(256) void base_kernel(const float* __restrict__ mean_v,
                                                   const float* __restrict__ Wo,
                                                   const float* __restrict__ bo,
                                                   float* __restrict__ base)
{
    int lane = threadIdx.x & 63, wv = threadIdx.x >> 6;
    int be = blockIdx.x * 4 + wv;
    int b  = be >> 9;
    int e  = be & (EE - 1);
    const float* mrow = mean_v + b * EE;
    const float* wrow = Wo + (size_t)e * EE;
    float acc = 0.0f;
#pragma unroll
    for (int j = 0; j < 8; j++) acc += mrow[lane + j * 64] * wrow[lane + j * 64];
#pragma unroll
    for (int off = 32; off > 0; off >>= 1) acc += __shfl_down(acc, off, 64);
    if (lane == 0) base[be] = acc + bo[e];
}

// ---------------------------------------------------------------------------
// K6b: broadcast base row to all l
// ---------------------------------------------------------------------------
__global__ __launch_bounds__(256) void bcast_kernel(const float* __restrict__ base,
                                                    float* __restrict__ out)
{
    size_t fi = ((size_t)blockIdx.x * 256 + threadIdx.x) * 4;
    int b  = (int)(fi >> 20);
    int e4 = (int)(fi & (EE - 1));
    float4 val = *(const float4*)(base + b * EE + e4);
    *(float4*)(out + fi) = val;
}

// ---------------------------------------------------------------------------
// K6c: combine chunk partials (online-softmax merge) + correction GEMV.
// ---------------------------------------------------------------------------
__global__ __launch_bounds__(256) void corr_kernel(const float* __restrict__ accpart,
                                                   const float* __restrict__ lpart,
                                                   const float* __restrict__ mpart,
                                                   const float* __restrict__ mean_v,
                                                   const int* __restrict__ top,
                                                   const float* __restrict__ Wo,
                                                   float* __restrict__ out)
{
    int bhu = blockIdx.x;
    int bh  = bhu / NT;
    int u   = bhu % NT;
    int h   = bh & (HH - 1);
    int b   = bh >> 3;
    int tid = threadIdx.x;
    int l   = top[bhu];

    __shared__ float delta[DD];
    if (tid < DD) {
        float m = NEG_INF;
#pragma unroll 8
        for (int c = 0; c < NCH; c++) m = fmaxf(m, mpart[(bh * NCH + c) * NT + u]);
        float den = 0.0f, num = 0.0f;
#pragma unroll 8
        for (int c = 0; c < NCH; c++) {
            float f = __expf(mpart[(bh * NCH + c) * NT + u] - m);
            den += lpart[(bh * NCH + c) * NT + u] * f;
            num += accpart[(((size_t)(bh * NCH + c)) * NT + u) * 64 + tid] * f;
        }
        delta[tid] = num / den - mean_v[bh * DD + tid];
    }
    __syncthreads();

    float* orow = out + ((size_t)(b * LL + l)) * EE;
#pragma unroll
    for (int rep = 0; rep < 2; rep++) {
        int e = tid + rep * 256;
        const float* wrow = Wo + (size_t)e * EE + h * DD;
        float acc = 0.0f;
#pragma unroll
        for (int d = 0; d < DD; d++) acc += delta[d] * wrow[d];
        atomicAdd(orow + e, acc);
    }
}

// ---------------------------------------------------------------------------
extern "C" void kernel_launch(void* const* d_in, const int* in_sizes, int n_in,
                              void* d_out, int out_size, void* d_ws, size_t ws_size,
                              hipStream_t stream)
{
    const float* query = (const float*)d_in[0];
    const float* key   = (const float*)d_in[1];
    const float* value = (const float*)d_in[2];
    const int*   idxs  = (const int*)d_in[3];
    const float* Wq = (const float*)d_in[4];
    const float* bq = (const float*)d_in[5];
    const float* Wk = (const float*)d_in[6];
    const float* bk = (const float*)d_in[7];
    const float* Wv = (const float*)d_in[8];
    const float* bv = (const float*)d_in[9];
    const float* Wo = (const float*)d_in[10];
    const float* bo = (const float*)d_in[11];
    float* out = (float*)d_out;

    // workspace layout (~62 MB)
    char* ws = (char*)d_ws;
    size_t off = 0;
    const size_t qkv_bytes = (size_t)BB * HH * LL * DD * sizeof(float); // 16 MB each
    float* q_ws = (float*)(ws + off); off += qkv_bytes;
    float* k_ws = (float*)(ws + off); off += qkv_bytes;
    float* v_ws = (float*)(ws + off); off += qkv_bytes;
    float* M_ws    = (float*)(ws + off); off += (size_t)BB * HH * LL * sizeof(float);
    int*   top_ws  = (int*)(ws + off);   off += (size_t)BB * HH * NT * sizeof(int);
    float* mean_ws = (float*)(ws + off); off += (size_t)BB * HH * DD * sizeof(float);
    float* vpart_ws = (float*)(ws + off); off += (size_t)BB * HH * MVC * DD * sizeof(float);
    float* mpart_ws = (float*)(ws + off); off += (size_t)BB * HH * NCH * NT * sizeof(float);
    float* lpart_ws = (float*)(ws + off); off += (size_t)BB * HH * NCH * NT * sizeof(float);
    float* accpart_ws = (float*)(ws + off); off += (size_t)BB * HH * NCH * NT * DD * sizeof(float);
    float* base_ws = (float*)(ws + off); off += (size_t)BB * EE * sizeof(float);

    // Converted-W planes (3 MB) alias the head of accpart_ws: wconv writes ->
    // proj reads -> (later) pv overwrites accpart -> corr reads. Stream-serial,
    // so the lifetime windows are disjoint; avoids growing ws_size.
    unsigned short* wcv_ws = (unsigned short*)accpart_ws;

    // K0: pre-convert W to bf16 hi+mid planes
    wconv_kernel<<<384, 256, 0, stream>>>(Wq, Wk, Wv, wcv_ws);
    // K1: QKV projections (single-barrier pipelined split-bf16 MFMA)
    proj_kernel<<<768, 256, 0, stream>>>(query, key, value, wcv_ws, bq, bk, bv,
                                         q_ws, k_ws, v_ws);
    // K2: mean of V (two-stage)
    meanv_part_kernel<<<BB * HH * MVC, 256, 0, stream>>>(v_ws, vpart_ws);
    meanv_comb_kernel<<<BB * HH, 64, 0, stream>>>(vpart_ws, mean_ws);
    // K3: sparsity measure
    measure_kernel<<<(LL / 4) * 32, 256, 0, stream>>>(q_ws, k_ws, idxs, M_ws);
    // K4: top-40 (single wave per bh)
    topk_kernel<<<BB * HH, 64, 0, stream>>>(M_ws, top_ws);
    // K5: split-K attention partials
    pv_kernel<<<BB * HH * NCH, 256, 0, stream>>>(q_ws, k_ws, v_ws, top_ws,
                                                 mpart_ws, lpart_ws, accpart_ws);
    // K6: output projection (base + broadcast + combine/correct)
    base_kernel<<<(BB * EE) / 4, 256, 0, stream>>>(mean_ws, Wo, bo, base_ws);
    bcast_kernel<<<(BB * LL * EE) / (256 * 4), 256, 0, stream>>>(base_ws, out);
    corr_kernel<<<BB * HH * NT, 256, 0, stream>>>(accpart_ws, lpart_ws, mpart_ws,
                                                  mean_ws, top_ws, Wo, out);
}

// Round 3
// 312.762 us; speedup vs baseline: 1.0282x; 1.0282x over previous
//
#include <hip/hip_runtime.h>
#include <hip/hip_bf16.h>
#include <math.h>

// Problem constants (fixed by reference)
constexpr int BB = 4;
constexpr int LL = 2048;
constexpr int EE = 512;
constexpr int HH = 8;
constexpr int DD = 64;
constexpr int UU = 40;    // sample count
constexpr int NT = 40;    // n_top
constexpr int NCH = 32;   // key chunks (64 keys each) for split-K attention
constexpr int CK = 64;    // keys per chunk
constexpr int MVC = 16;   // L-chunks for meanv stage 1 (128 rows each)
constexpr float NEG_INF = -3.0e38f;

typedef __attribute__((ext_vector_type(8))) short bf8_t;  // 8 bf16 (4 VGPR)
typedef __attribute__((ext_vector_type(4))) float f4_t;   // MFMA C/D frag

// ---------------------------------------------------------------------------
// split helpers: f32 = hi(RNE bf16) + mid(trunc bf16). Bit-identical math to
// the previous rounds (absmax must stay at 2.44e-4).
// ---------------------------------------------------------------------------
__device__ __forceinline__ void split2pair(float x0, float x1, uint& hp, uint& mp)
{
    uint xb0 = __float_as_uint(x0), xb1 = __float_as_uint(x1);
    uint hb0 = xb0 + 0x7fffu + ((xb0 >> 16) & 1u);
    uint hb1 = xb1 + 0x7fffu + ((xb1 >> 16) & 1u);
    hp = __builtin_amdgcn_perm(hb1, hb0, 0x07060302u);            // [h1.hi16|h0.hi16]
    float r0 = x0 - __uint_as_float(hb0 & 0xffff0000u);
    float r1 = x1 - __uint_as_float(hb1 & 0xffff0000u);
    mp = __builtin_amdgcn_perm(__float_as_uint(r1), __float_as_uint(r0), 0x07060302u);
}

__device__ __forceinline__ void gload16(const void* g, void* l)
{
    __builtin_amdgcn_global_load_lds(
        (const __attribute__((address_space(1))) unsigned int*)g,
        (__attribute__((address_space(3))) unsigned int*)l, 16, 0, 0);
}

__device__ __forceinline__ int swz(int row, int c)
{
    return row * 64 + (((c ^ row ^ (row >> 2)) & 3) << 4);
}

// ---------------------------------------------------------------------------
// K0: pre-convert Wq/Wk/Wv (f32 [512][512]) to bf16 hi+mid planes.
// Output layout wcv[z][plane][512*512] ushort, z in {q,k,v}, plane in {hi,mid}.
// ---------------------------------------------------------------------------
__global__ __launch_bounds__(256) void wconv_kernel(
    const float* __restrict__ Wq, const float* __restrict__ Wk,
    const float* __restrict__ Wv, unsigned short* __restrict__ wcv)
{
    const int gi  = blockIdx.x * 256 + threadIdx.x;   // 0..98303
    const int z   = gi >> 15;                         // 32768 threads per matrix
    const int off = (gi & 32767) * 8;
    const float* W = (z == 0) ? Wq : (z == 1 ? Wk : Wv);
    float x[8];
    *(float4*)(x)     = *(const float4*)(W + off);
    *(float4*)(x + 4) = *(const float4*)(W + off + 4);
    uint hp[4], mp[4];
#pragma unroll
    for (int p = 0; p < 4; p++) split2pair(x[2 * p], x[2 * p + 1], hp[p], mp[p]);
    unsigned short* Wh = wcv + (size_t)z * 524288;
    *(uint4*)(Wh + off)          = make_uint4(hp[0], hp[1], hp[2], hp[3]);
    *(uint4*)(Wh + 262144 + off) = make_uint4(mp[0], mp[1], mp[2], mp[3]);
}

// ---------------------------------------------------------------------------
// K1: fused QKV projection. 128x128x32 tile, 4 waves, 3-product split-bf16
// MFMA. R1 structure restored (measured 56us): 49KB LDS -> 3 blocks/CU.
// R2's single-barrier 64KB variant cut occupancy to 2 blocks/CU and LOST 7us
// (m132-style regression) — cross-block wave overlap matters more than
// explicit pipelining here. Do not re-raise LDS past ~53KB.
//  - B (weights) pre-converted by K0; staged via global_load_lds (w=16) with
//    inverse-swizzled SOURCE addresses, double-buffered (2x16KB).
//  - A-regs + next B tile prefetched AFTER the 2nd barrier so the compiler's
//    vmcnt(0)-before-barrier doesn't drain them.
// ---------------------------------------------------------------------------
__global__ __launch_bounds__(256, 3) void proj_kernel(
    const float* __restrict__ Xq, const float* __restrict__ Xk, const float* __restrict__ Xv,
    const unsigned short* __restrict__ Wcv,
    const float* __restrict__ bq, const float* __restrict__ bk, const float* __restrict__ bv,
    float* __restrict__ Oq, float* __restrict__ Ok, float* __restrict__ Ov)
{
    // XCD-grouped decode: 768 = 8 xcd * 96; same (yi,zi) -> same xcd.
    const int bid = blockIdx.x;
    const int xg  = bid & 7;
    const int s   = bid >> 3;            // 0..95
    const int yz  = xg * 24 + (s >> 2);  // 0..191
    const int zi  = yz >> 6;             // 0..2
    const int yi  = yz & 63;
    const int m0  = yi * 128;
    const int n0  = (s & 3) * 128;

    const float* X; const float* bias; float* O;
    if (zi == 0)      { X = Xq; bias = bq; O = Oq; }
    else if (zi == 1) { X = Xk; bias = bk; O = Ok; }
    else              { X = Xv; bias = bv; O = Ov; }
    const unsigned short* Wh = Wcv + (size_t)zi * 524288;
    const unsigned short* Wm = Wh + 262144;

    __shared__ char ldsmem[49152];
    char* const LA = ldsmem;           // A tile: hi@0, mid@8192 (16KB)
    char* const LB = ldsmem + 16384;   // B tiles: 2 buffers x (hi 8KB + mid 8KB)

    const int tid  = threadIdx.x;
    const int lane = tid & 63;
    const int wave = tid >> 6;

    // A staging (reg-staged: needs on-the-fly split): thread covers row tid>>1,
    // 16 f32 at half (tid&1); swizzled LDS writes.
    const int srow  = tid >> 1;
    const int shalf = tid & 1;
    const int w0 = swz(srow, shalf * 2);
    const int w1 = swz(srow, shalf * 2 + 1);
    const float* Aptr = X + (size_t)(m0 + srow) * EE + shalf * 16;

    // B staging via global_load_lds: linear dest, inverse-swizzled SOURCE.
    const int r0 = tid >> 2;
    const int r1 = 64 + r0;
    const int c0 = (tid & 3) ^ ((r0 ^ (r0 >> 2)) & 3);
    const int c1 = (tid & 3) ^ ((r1 ^ (r1 >> 2)) & 3);
    const unsigned short* bh0 = Wh + (size_t)(n0 + r0) * EE + c0 * 8;
    const unsigned short* bh1 = Wh + (size_t)(n0 + r1) * EE + c1 * 8;
    const unsigned short* bm0 = Wm + (size_t)(n0 + r0) * EE + c0 * 8;
    const unsigned short* bm1 = Wm + (size_t)(n0 + r1) * EE + c1 * 8;
    const int ldst = tid * 16;         // linear dest: wave-uniform base + lane*16

    const int rxor = ((((lane >> 4) ^ lane ^ (lane >> 2)) & 3) << 4);
    const int arow = (wave >> 1) * 64 + (lane & 15);
    const int brow = (wave & 1) * 64 + (lane & 15);

    f4_t acc[4][4];
#pragma unroll
    for (int i = 0; i < 4; i++)
#pragma unroll
        for (int j = 0; j < 4; j++) acc[i][j] = (f4_t)0.0f;

    // prologue: A regs + B tile for kt=0 (into buffer 0)
    float fa[16];
#pragma unroll
    for (int q = 0; q < 4; q++)
        *(float4*)(fa + q * 4) = *(const float4*)(Aptr + q * 4);
    gload16(bh0, LB + ldst);
    gload16(bh1, LB + 4096 + ldst);
    gload16(bm0, LB + 8192 + ldst);
    gload16(bm1, LB + 12288 + ldst);

    int parity = 0;
#pragma unroll 2
    for (int kt = 0; kt < EE; kt += 32) {
        // convert current A regs (RNE hi + trunc mid, perm-packed)
        uint ahu[8], amu[8];
#pragma unroll
        for (int p = 0; p < 8; p++)
            split2pair(fa[2 * p], fa[2 * p + 1], ahu[p], amu[p]);

        __syncthreads();   // WAR: previous iteration's A-frag reads done
        *(uint4*)(LA +    0 + w0) = make_uint4(ahu[0], ahu[1], ahu[2], ahu[3]);
        *(uint4*)(LA +    0 + w1) = make_uint4(ahu[4], ahu[5], ahu[6], ahu[7]);
        *(uint4*)(LA + 8192 + w0) = make_uint4(amu[0], amu[1], amu[2], amu[3]);
        *(uint4*)(LA + 8192 + w1) = make_uint4(amu[4], amu[5], amu[6], amu[7]);
        __syncthreads();   // A visible; vmcnt(0) drain completes B(kt)

        // prefetch next K-step AFTER the barrier (not drained by it):
        // fa first (so its waitcnt doesn't force draining the B lds-loads).
        if (kt + 32 < EE) {
            const int kn = kt + 32;
#pragma unroll
            for (int q = 0; q < 4; q++)
                *(float4*)(fa + q * 4) = *(const float4*)(Aptr + kn + q * 4);
            char* Bn = LB + (parity ^ 1) * 16384;
            gload16(bh0 + kn, Bn + ldst);
            gload16(bh1 + kn, Bn + 4096 + ldst);
            gload16(bm0 + kn, Bn + 8192 + ldst);
            gload16(bm1 + kn, Bn + 12288 + ldst);
        }

        char* const Bb = LB + parity * 16384;
        bf8_t af[4][2];
#pragma unroll
        for (int i = 0; i < 4; i++) {
            const int ro = (arow + i * 16) * 64 + rxor;
            af[i][0] = *(const bf8_t*)(LA +    0 + ro);
            af[i][1] = *(const bf8_t*)(LA + 8192 + ro);
        }
#pragma unroll
        for (int j = 0; j < 4; j++) {
            const int ro = (brow + j * 16) * 64 + rxor;
            bf8_t bh_ = *(const bf8_t*)(Bb +    0 + ro);
            bf8_t bm_ = *(const bf8_t*)(Bb + 8192 + ro);
#pragma unroll
            for (int i = 0; i < 4; i++) {
                f4_t c = acc[i][j];
                c = __builtin_amdgcn_mfma_f32_16x16x32_bf16(af[i][0], bh_, c, 0, 0, 0); // hh
                c = __builtin_amdgcn_mfma_f32_16x16x32_bf16(af[i][0], bm_, c, 0, 0, 0); // hm
                c = __builtin_amdgcn_mfma_f32_16x16x32_bf16(af[i][1], bh_, c, 0, 0, 0); // mh
                acc[i][j] = c;
            }
        }
        parity ^= 1;
    }

#pragma unroll
    for (int j = 0; j < 4; j++) {
        const int n  = n0 + (wave & 1) * 64 + j * 16 + (lane & 15);
        const float bn = bias[n];
        const int h_ = n >> 6, d_ = n & 63;
#pragma unroll
        for (int i = 0; i < 4; i++) {
            const int mb = m0 + (wave >> 1) * 64 + i * 16 + ((lane >> 4) << 2);
#pragma unroll
            for (int r = 0; r < 4; r++) {
                const int m  = mb + r;
                const int b_ = m >> 11;
                const int l_ = m & (LL - 1);
                O[(((size_t)(b_ * HH + h_) * LL + l_) << 6) + d_] = acc[i][j][r] + bn;
            }
        }
    }
}

// ---------------------------------------------------------------------------
// K2a: mean of V stage 1 — 512 blocks = (lchunk 0..15) x (bh 0..31).
// ---------------------------------------------------------------------------
__global__ __launch_bounds__(256) void meanv_part_kernel(const float* __restrict__ v,
                                                         float* __restrict__ vpart)
{
    const int bh    = blockIdx.x & 31;
    const int chunk = blockIdx.x >> 5;
    const int d  = threadIdx.x & 63;
    const int wv = threadIdx.x >> 6;
    const float* base = v + ((size_t)bh * LL + chunk * 128 + wv * 32) * DD + d;
    float acc = 0.0f;
#pragma unroll
    for (int i = 0; i < 32; i++) acc += base[i * DD];
    __shared__ float red[4][DD];
    red[wv][d] = acc;
    __syncthreads();
    if (wv == 0)
        vpart[(size_t)(chunk * 32 + bh) * DD + d]
            = red[0][d] + red[1][d] + red[2][d] + red[3][d];
}

// ---------------------------------------------------------------------------
// K2b: mean of V stage 2 — combine 16 partials per (bh,d).
// ---------------------------------------------------------------------------
__global__ __launch_bounds__(64) void meanv_comb_kernel(const float* __restrict__ vpart,
                                                        float* __restrict__ mean_v)
{
    const int bh = blockIdx.x;
    const int d  = threadIdx.x;
    float s = 0.0f;
#pragma unroll
    for (int c = 0; c < MVC; c++) s += vpart[(size_t)(c * 32 + bh) * DD + d];
    mean_v[bh * DD + d] = s * (1.0f / (float)LL);
}

// ---------------------------------------------------------------------------
// K3: sparsity measure M[b,h,l] = max_s(q.k_sample) - sum_s(q.k_sample)/L
// One wave per (b,h,l). Lane map: 8 samples x 8 d-chunks.
// ---------------------------------------------------------------------------
__global__ __launch_bounds__(256) void measure_kernel(const float* __restrict__ q,
                                                      const float* __restrict__ k,
                                                      const int* __restrict__ idx_sample,
                                                      float* __restrict__ M)
{
    int bh   = blockIdx.x & 31;
    int lc   = blockIdx.x >> 5;
    int lane = threadIdx.x & 63;
    int wv   = threadIdx.x >> 6;
    int l    = lc * 4 + wv;
    int s8   = lane >> 3;   // sample slot 0..7
    int c    = lane & 7;    // d-chunk 0..7

    const float* qrow = q + ((size_t)bh * LL + l) * DD + c * 8;
    float4 q0 = *(const float4*)(qrow);
    float4 q1 = *(const float4*)(qrow + 4);

    const float* kbase = k + (size_t)bh * LL * DD;
    const int*   irow  = idx_sample + l * UU;

    float mx = NEG_INF, sum = 0.0f;
#pragma unroll
    for (int it = 0; it < UU; it += 8) {
        int ki = irow[it + s8];
        const float* krow = kbase + (size_t)ki * DD + c * 8;
        float4 k0 = *(const float4*)(krow);
        float4 k1 = *(const float4*)(krow + 4);
        float p = q0.x*k0.x + q0.y*k0.y + q0.z*k0.z + q0.w*k0.w
                + q1.x*k1.x + q1.y*k1.y + q1.z*k1.z + q1.w*k1.w;
        p += __shfl_xor(p, 1, 64);
        p += __shfl_xor(p, 2, 64);
        p += __shfl_xor(p, 4, 64);
        mx = fmaxf(mx, p);
        sum += p;
    }
    mx  = fmaxf(mx, __shfl_xor(mx, 8, 64));
    sum += __shfl_xor(sum, 8, 64);
    mx  = fmaxf(mx, __shfl_xor(mx, 16, 64));
    sum += __shfl_xor(sum, 16, 64);
    mx  = fmaxf(mx, __shfl_xor(mx, 32, 64));
    sum += __shfl_xor(sum, 32, 64);

    if (lane == 0) M[bh * LL + l] = mx - sum * (1.0f / (float)LL);
}

// ---------------------------------------------------------------------------
// K4: top-40 per (b,h), single-wave register version.
// ---------------------------------------------------------------------------
__global__ __launch_bounds__(64) void topk_kernel(const float* __restrict__ M,
                                                  int* __restrict__ top)
{
    const int bh   = blockIdx.x;
    const int lane = threadIdx.x;

    unsigned long long keys[32];
#pragma unroll
    for (int i = 0; i < 32; i++) {
        int idx = i * 64 + lane;
        uint u  = __float_as_uint(M[bh * LL + idx]);
        uint sv = (u & 0x80000000u) ? ~u : (u | 0x80000000u);
        keys[i] = ((unsigned long long)sv << 32) | (uint)(LL - 1 - idx);
    }
    unsigned long long lmax = 0ull;
#pragma unroll
    for (int i = 0; i < 32; i++) lmax = (keys[i] > lmax) ? keys[i] : lmax;

    for (int it = 0; it < NT; it++) {
        unsigned long long g = lmax;
#pragma unroll
        for (int off = 1; off < 64; off <<= 1) {
            unsigned long long o = __shfl_xor(g, off, 64);
            g = (o > g) ? o : g;
        }
        if (lane == 0) top[bh * NT + it] = LL - 1 - (int)(g & 0xffffffffu);
#pragma unroll
        for (int i = 0; i < 32; i++) if (keys[i] == g) keys[i] = 0ull;
        lmax = 0ull;
#pragma unroll
        for (int i = 0; i < 32; i++) lmax = (keys[i] > lmax) ? keys[i] : lmax;
    }
}

// ---------------------------------------------------------------------------
// K5: flash-style split-K attention partials. PV phase is the R0-measured
// scalar body (the R1 float4 rewrite cost ~10-16us on the total — reverted).
// ---------------------------------------------------------------------------
__global__ __launch_bounds__(256) void pv_kernel(const float* __restrict__ q,
                                                 const float* __restrict__ k,
                                                 const float* __restrict__ v,
                                                 const int* __restrict__ top,
                                                 float* __restrict__ mpart,
                                                 float* __restrict__ lpart,
                                                 float* __restrict__ accpart)
{
    const int bh    = blockIdx.x & 31;
    const int chunk = blockIdx.x >> 5;
    const int tid   = threadIdx.x;
    const int lane  = tid & 63, wv = tid >> 6;

    __shared__ float qs[NT][DD];        // 10240 B
    __shared__ float sc[NT][CK + 4];    // 10880 B

    for (int i = tid; i < NT * DD / 4; i += 256) {
        int u  = i >> 4;
        int d4 = (i & 15) * 4;
        int l  = top[bh * NT + u];
        *(float4*)&qs[u][d4] = *(const float4*)(q + ((size_t)bh * LL + l) * DD + d4);
    }
    __syncthreads();

    {
        const int key  = tid >> 2;
        const int dseg = tid & 3;
        const float* krow = k + ((size_t)bh * LL + chunk * CK + key) * DD + dseg * 16;
        float4 k0 = *(const float4*)(krow);
        float4 k1 = *(const float4*)(krow + 4);
        float4 k2 = *(const float4*)(krow + 8);
        float4 k3 = *(const float4*)(krow + 12);
#pragma unroll 8
        for (int u = 0; u < NT; u++) {
            const float* qrow = &qs[u][dseg * 16];
            float4 q0 = *(const float4*)(qrow);
            float4 q1 = *(const float4*)(qrow + 4);
            float4 q2 = *(const float4*)(qrow + 8);
            float4 q3 = *(const float4*)(qrow + 12);
            float p = k0.x*q0.x + k0.y*q0.y + k0.z*q0.z + k0.w*q0.w
                    + k1.x*q1.x + k1.y*q1.y + k1.z*q1.z + k1.w*q1.w
                    + k2.x*q2.x + k2.y*q2.y + k2.z*q2.z + k2.w*q2.w
                    + k3.x*q3.x + k3.y*q3.y + k3.z*q3.z + k3.w*q3.w;
            p += __shfl_xor(p, 1, 64);
            p += __shfl_xor(p, 2, 64);
            if (dseg == 0) sc[u][key] = p;
        }
    }
    __syncthreads();

#pragma unroll
    for (int i = 0; i < 10; i++) {
        const int u = wv * 10 + i;
        float val = sc[u][lane];
        float mx = val;
        mx = fmaxf(mx, __shfl_xor(mx, 1, 64));
        mx = fmaxf(mx, __shfl_xor(mx, 2, 64));
        mx = fmaxf(mx, __shfl_xor(mx, 4, 64));
        mx = fmaxf(mx, __shfl_xor(mx, 8, 64));
        mx = fmaxf(mx, __shfl_xor(mx, 16, 64));
        mx = fmaxf(mx, __shfl_xor(mx, 32, 64));
        float e = __expf(val - mx);
        sc[u][lane] = e;
        float s = e;
        s += __shfl_xor(s, 1, 64);
        s += __shfl_xor(s, 2, 64);
        s += __shfl_xor(s, 4, 64);
        s += __shfl_xor(s, 8, 64);
        s += __shfl_xor(s, 16, 64);
        s += __shfl_xor(s, 32, 64);
        if (lane == 0) {
            mpart[(bh * NCH + chunk) * NT + u] = mx;
            lpart[(bh * NCH + chunk) * NT + u] = s;
        }
    }
    __syncthreads();

    {
        float pacc[10];
#pragma unroll
        for (int i = 0; i < 10; i++) pacc[i] = 0.0f;
        const float* vbase = v + ((size_t)bh * LL + chunk * CK) * DD;
#pragma unroll 8
        for (int t = 0; t < CK; t++) {
            float vval = vbase[(size_t)t * DD + lane];
#pragma unroll
            for (int i = 0; i < 10; i++) pacc[i] += sc[wv * 10 + i][t] * vval;
        }
#pragma unroll
        for (int i = 0; i < 10; i++) {
            const int u = wv * 10 + i;
            accpart[(((size_t)(bh * NCH + chunk)) * NT + u) * 64 + lane] = pacc[i];
        }
    }
}

// ---------------------------------------------------------------------------
// K6a: base output row per batch: base[b,e] = meanctx[b,:] . Wo[e,:] + bo[e]
// ---------------------------------------------------------------------------
__global__ __launch_bounds__(256) void base_kernel(const float* __restrict__ mean_v,
                                                   const float* __restrict__ Wo,
                                                   const float* __restrict__ bo,
                                                   float* __restrict__ base)
{
    int lane = threadIdx.x & 63, wv = threadIdx.x >> 6;
    int be = blockIdx.x * 4 + wv;
    int b  = be >> 9;
    int e  = be & (EE - 1);
    const float* mrow = mean_v + b * EE;
    const float* wrow = Wo + (size_t)e * EE;
    float acc = 0.0f;
#pragma unroll
    for (int j = 0; j < 8; j++) acc += mrow[lane + j * 64] * wrow[lane + j * 64];
#pragma unroll
    for (int off = 32; off > 0; off >>= 1) acc += __shfl_down(acc, off, 64);
    if (lane == 0) base[be] = acc + bo[e];
}

// ---------------------------------------------------------------------------
// K6b: broadcast base row to all l
// ---------------------------------------------------------------------------
__global__ __launch_bounds__(256) void bcast_kernel(const float* __restrict__ base,
                                                    float* __restrict__ out)
{
    size_t fi = ((size_t)blockIdx.x * 256 + threadIdx.x) * 4;
    int b  = (int)(fi >> 20);
    int e4 = (int)(fi & (EE - 1));
    float4 val = *(const float4*)(base + b * EE + e4);
    *(float4*)(out + fi) = val;
}

// ---------------------------------------------------------------------------
// K6c: combine chunk partials + correction GEMV — REWRITTEN.
// Old: 1280 blocks, each scans Wo with lane-index = e (stride-2KB,
// uncoalesced, ~160MB of scattered traffic) and only 64/256 threads active
// in the delta phase. New: 128 blocks = (e-chunk 0..3) x (bh 0..31).
//  - delta[40][64] computed by all 4 waves (u strided by wave), coalesced
//    accpart reads (lane = d).
//  - Wo slice [128 e-rows][64 d] staged to LDS coalesced, padded [128][65]
//    (stride 65 -> bank (el+d)%32, conflict-free).
//  - per-thread: 20 u x 64 d FMA from LDS; same accumulation order and same
//    atomicAdd set as before (numerics preserved).
// Wo traffic: 160MB -> 16MB (4x redundancy over 4MB slice set).
// ---------------------------------------------------------------------------
__global__ __launch_bounds__(256) void corr_kernel(const float* __restrict__ accpart,
                                                   const float* __restrict__ lpart,
                                                   const float* __restrict__ mpart,
                                                   const float* __restrict__ mean_v,
                                                   const int* __restrict__ top,
                                                   const float* __restrict__ Wo,
                                                   float* __restrict__ out)
{
    const int bh  = blockIdx.x & 31;
    const int ec  = blockIdx.x >> 5;     // 0..3
    const int h   = bh & (HH - 1);
    const int b   = bh >> 3;
    const int tid = threadIdx.x;

    __shared__ float delta[NT][DD + 1];   // 10400 B
    __shared__ float wot[128][DD + 1];    // 33280 B
    __shared__ int   ltab[NT];

    // phase 1: delta[u][d] for all u (waves stride u by 4), lane = d
    {
        const int ug = tid >> 6;
        const int d  = tid & 63;
        for (int u = ug; u < NT; u += 4) {
            const float* mp = mpart + (size_t)bh * NCH * NT + u;
            const float* lp = lpart + (size_t)bh * NCH * NT + u;
            float m = NEG_INF;
#pragma unroll 8
            for (int c = 0; c < NCH; c++) m = fmaxf(m, mp[c * NT]);
            float den = 0.0f, num = 0.0f;
#pragma unroll 8
            for (int c = 0; c < NCH; c++) {
                float f = __expf(mp[c * NT] - m);
                den += lp[c * NT] * f;
                num += accpart[(((size_t)(bh * NCH + c)) * NT + u) * 64 + d] * f;
            }
            delta[u][d] = num / den - mean_v[bh * DD + d];
        }
    }
    if (tid < NT) ltab[tid] = top[bh * NT + tid];

    // stage Wo[e0..e0+128)[h*64..h*64+64) coalesced (16 threads x 16B per row)
    const int e0 = ec * 128;
#pragma unroll
    for (int p = 0; p < 8; p++) {
        const int r  = p * 16 + (tid >> 4);
        const int c4 = (tid & 15) * 4;
        *(float4*)&wot[r][c4] = *(const float4*)(Wo + (size_t)(e0 + r) * EE + h * DD + c4);
    }
    __syncthreads();

    // phase 2: thread = (e_local = tid>>1, u-half = tid&1 -> 20 u's)
    const int el = tid >> 1;
    const int u0 = (tid & 1) * 20;
    float* orowbase = out + (size_t)b * LL * EE + e0 + el;
#pragma unroll 4
    for (int uu = 0; uu < 20; uu++) {
        const int u = u0 + uu;
        float acc = 0.0f;
#pragma unroll
        for (int d = 0; d < DD; d++) acc += delta[u][d] * wot[el][d];
        atomicAdd(orowbase + (size_t)ltab[u] * EE, acc);
    }
}

// ---------------------------------------------------------------------------
extern "C" void kernel_launch(void* const* d_in, const int* in_sizes, int n_in,
                              void* d_out, int out_size, void* d_ws, size_t ws_size,
                              hipStream_t stream)
{
    const float* query = (const float*)d_in[0];
    const float* key   = (const float*)d_in[1];
    const float* value = (const float*)d_in[2];
    const int*   idxs  = (const int*)d_in[3];
    const float* Wq = (const float*)d_in[4];
    const float* bq = (const float*)d_in[5];
    const float* Wk = (const float*)d_in[6];
    const float* bk = (const float*)d_in[7];
    const float* Wv = (const float*)d_in[8];
    const float* bv = (const float*)d_in[9];
    const float* Wo = (const float*)d_in[10];
    const float* bo = (const float*)d_in[11];
    float* out = (float*)d_out;

    // workspace layout (~62 MB)
    char* ws = (char*)d_ws;
    size_t off = 0;
    const size_t qkv_bytes = (size_t)BB * HH * LL * DD * sizeof(float); // 16 MB each
    float* q_ws = (float*)(ws + off); off += qkv_bytes;
    float* k_ws = (float*)(ws + off); off += qkv_bytes;
    float* v_ws = (float*)(ws + off); off += qkv_bytes;
    float* M_ws    = (float*)(ws + off); off += (size_t)BB * HH * LL * sizeof(float);
    int*   top_ws  = (int*)(ws + off);   off += (size_t)BB * HH * NT * sizeof(int);
    float* mean_ws = (float*)(ws + off); off += (size_t)BB * HH * DD * sizeof(float);
    float* vpart_ws = (float*)(ws + off); off += (size_t)BB * HH * MVC * DD * sizeof(float);
    float* mpart_ws = (float*)(ws + off); off += (size_t)BB * HH * NCH * NT * sizeof(float);
    float* lpart_ws = (float*)(ws + off); off += (size_t)BB * HH * NCH * NT * sizeof(float);
    float* accpart_ws = (float*)(ws + off); off += (size_t)BB * HH * NCH * NT * DD * sizeof(float);
    float* base_ws = (float*)(ws + off); off += (size_t)BB * EE * sizeof(float);

    // Converted-W planes (3 MB) alias the head of accpart_ws: wconv writes ->
    // proj reads -> (later) pv overwrites accpart -> corr reads. Stream-serial,
    // so the lifetime windows are disjoint; avoids growing ws_size.
    unsigned short* wcv_ws = (unsigned short*)accpart_ws;

    // K0: pre-convert W to bf16 hi+mid planes
    wconv_kernel<<<384, 256, 0, stream>>>(Wq, Wk, Wv, wcv_ws);
    // K1: QKV projections (split-bf16 MFMA, 3 products, gload_lds B, prefetch)
    proj_kernel<<<768, 256, 0, stream>>>(query, key, value, wcv_ws, bq, bk, bv,
                                         q_ws, k_ws, v_ws);
    // K2: mean of V (two-stage)
    meanv_part_kernel<<<BB * HH * MVC, 256, 0, stream>>>(v_ws, vpart_ws);
    meanv_comb_kernel<<<BB * HH, 64, 0, stream>>>(vpart_ws, mean_ws);
    // K3: sparsity measure
    measure_kernel<<<(LL / 4) * 32, 256, 0, stream>>>(q_ws, k_ws, idxs, M_ws);
    // K4: top-40 (single wave per bh)
    topk_kernel<<<BB * HH, 64, 0, stream>>>(M_ws, top_ws);
    // K5: split-K attention partials
    pv_kernel<<<BB * HH * NCH, 256, 0, stream>>>(q_ws, k_ws, v_ws, top_ws,
                                                 mpart_ws, lpart_ws, accpart_ws);
    // K6: output projection (base + broadcast + combine/correct)
    base_kernel<<<(BB * EE) / 4, 256, 0, stream>>>(mean_ws, Wo, bo, base_ws);
    bcast_kernel<<<(BB * LL * EE) / (256 * 4), 256, 0, stream>>>(base_ws, out);
    corr_kernel<<<128, 256, 0, stream>>>(accpart_ws, lpart_ws, mpart_ws,
                                         mean_ws, top_ws, Wo, out);
}

// Round 4
// 272.026 us; speedup vs baseline: 1.1822x; 1.1497x over previous
//
#include <hip/hip_runtime.h>
#include <hip/hip_bf16.h>
#include <math.h>

// Problem constants (fixed by reference)
constexpr int BB = 4;
constexpr int LL = 2048;
constexpr int EE = 512;
constexpr int HH = 8;
constexpr int DD = 64;
constexpr int UU = 40;    // sample count
constexpr int NT = 40;    // n_top
constexpr int NCH = 32;   // key chunks (64 keys each) for split-K attention
constexpr int CK = 64;    // keys per chunk
constexpr int MVC = 16;   // L-chunks for meanv stage 1 (128 rows each)
constexpr float NEG_INF = -3.0e38f;

typedef __attribute__((ext_vector_type(8))) short bf8_t;  // 8 bf16 (4 VGPR)
typedef __attribute__((ext_vector_type(4))) float f4_t;   // MFMA C/D frag

// ---------------------------------------------------------------------------
// split helpers: f32 = hi(RNE bf16) + mid(trunc bf16). Bit-identical math to
// the previous rounds (absmax must stay at 2.44e-4).
// ---------------------------------------------------------------------------
__device__ __forceinline__ void split2pair(float x0, float x1, uint& hp, uint& mp)
{
    uint xb0 = __float_as_uint(x0), xb1 = __float_as_uint(x1);
    uint hb0 = xb0 + 0x7fffu + ((xb0 >> 16) & 1u);
    uint hb1 = xb1 + 0x7fffu + ((xb1 >> 16) & 1u);
    hp = __builtin_amdgcn_perm(hb1, hb0, 0x07060302u);            // [h1.hi16|h0.hi16]
    float r0 = x0 - __uint_as_float(hb0 & 0xffff0000u);
    float r1 = x1 - __uint_as_float(hb1 & 0xffff0000u);
    mp = __builtin_amdgcn_perm(__float_as_uint(r1), __float_as_uint(r0), 0x07060302u);
}

__device__ __forceinline__ void gload16(const void* g, void* l)
{
    __builtin_amdgcn_global_load_lds(
        (const __attribute__((address_space(1))) unsigned int*)g,
        (__attribute__((address_space(3))) unsigned int*)l, 16, 0, 0);
}

__device__ __forceinline__ int swz(int row, int c)
{
    return row * 64 + (((c ^ row ^ (row >> 2)) & 3) << 4);
}

// ---------------------------------------------------------------------------
// K0: pre-convert Wq/Wk/Wv (f32 [512][512]) to bf16 hi+mid planes.
// ---------------------------------------------------------------------------
__global__ __launch_bounds__(256) void wconv_kernel(
    const float* __restrict__ Wq, const float* __restrict__ Wk,
    const float* __restrict__ Wv, unsigned short* __restrict__ wcv)
{
    const int gi  = blockIdx.x * 256 + threadIdx.x;   // 0..98303
    const int z   = gi >> 15;                         // 32768 threads per matrix
    const int off = (gi & 32767) * 8;
    const float* W = (z == 0) ? Wq : (z == 1 ? Wk : Wv);
    float x[8];
    *(float4*)(x)     = *(const float4*)(W + off);
    *(float4*)(x + 4) = *(const float4*)(W + off + 4);
    uint hp[4], mp[4];
#pragma unroll
    for (int p = 0; p < 4; p++) split2pair(x[2 * p], x[2 * p + 1], hp[p], mp[p]);
    unsigned short* Wh = wcv + (size_t)z * 524288;
    *(uint4*)(Wh + off)          = make_uint4(hp[0], hp[1], hp[2], hp[3]);
    *(uint4*)(Wh + 262144 + off) = make_uint4(mp[0], mp[1], mp[2], mp[3]);
}

// ---------------------------------------------------------------------------
// K1: fused QKV projection. 128x128x32 tile, 4 waves, 3-product split-bf16
// MFMA. R1 structure (measured 56-57us): 49KB LDS -> 3 blocks/CU. Do not
// re-raise LDS past ~53KB (R2's 64KB variant lost 7us to occupancy).
// ---------------------------------------------------------------------------
__global__ __launch_bounds__(256, 3) void proj_kernel(
    const float* __restrict__ Xq, const float* __restrict__ Xk, const float* __restrict__ Xv,
    const unsigned short* __restrict__ Wcv,
    const float* __restrict__ bq, const float* __restrict__ bk, const float* __restrict__ bv,
    float* __restrict__ Oq, float* __restrict__ Ok, float* __restrict__ Ov)
{
    // XCD-grouped decode: 768 = 8 xcd * 96; same (yi,zi) -> same xcd.
    const int bid = blockIdx.x;
    const int xg  = bid & 7;
    const int s   = bid >> 3;            // 0..95
    const int yz  = xg * 24 + (s >> 2);  // 0..191
    const int zi  = yz >> 6;             // 0..2
    const int yi  = yz & 63;
    const int m0  = yi * 128;
    const int n0  = (s & 3) * 128;

    const float* X; const float* bias; float* O;
    if (zi == 0)      { X = Xq; bias = bq; O = Oq; }
    else if (zi == 1) { X = Xk; bias = bk; O = Ok; }
    else              { X = Xv; bias = bv; O = Ov; }
    const unsigned short* Wh = Wcv + (size_t)zi * 524288;
    const unsigned short* Wm = Wh + 262144;

    __shared__ char ldsmem[49152];
    char* const LA = ldsmem;           // A tile: hi@0, mid@8192 (16KB)
    char* const LB = ldsmem + 16384;   // B tiles: 2 buffers x (hi 8KB + mid 8KB)

    const int tid  = threadIdx.x;
    const int lane = tid & 63;
    const int wave = tid >> 6;

    const int srow  = tid >> 1;
    const int shalf = tid & 1;
    const int w0 = swz(srow, shalf * 2);
    const int w1 = swz(srow, shalf * 2 + 1);
    const float* Aptr = X + (size_t)(m0 + srow) * EE + shalf * 16;

    const int r0 = tid >> 2;
    const int r1 = 64 + r0;
    const int c0 = (tid & 3) ^ ((r0 ^ (r0 >> 2)) & 3);
    const int c1 = (tid & 3) ^ ((r1 ^ (r1 >> 2)) & 3);
    const unsigned short* bh0 = Wh + (size_t)(n0 + r0) * EE + c0 * 8;
    const unsigned short* bh1 = Wh + (size_t)(n0 + r1) * EE + c1 * 8;
    const unsigned short* bm0 = Wm + (size_t)(n0 + r0) * EE + c0 * 8;
    const unsigned short* bm1 = Wm + (size_t)(n0 + r1) * EE + c1 * 8;
    const int ldst = tid * 16;         // linear dest: wave-uniform base + lane*16

    const int rxor = ((((lane >> 4) ^ lane ^ (lane >> 2)) & 3) << 4);
    const int arow = (wave >> 1) * 64 + (lane & 15);
    const int brow = (wave & 1) * 64 + (lane & 15);

    f4_t acc[4][4];
#pragma unroll
    for (int i = 0; i < 4; i++)
#pragma unroll
        for (int j = 0; j < 4; j++) acc[i][j] = (f4_t)0.0f;

    // prologue: A regs + B tile for kt=0 (into buffer 0)
    float fa[16];
#pragma unroll
    for (int q = 0; q < 4; q++)
        *(float4*)(fa + q * 4) = *(const float4*)(Aptr + q * 4);
    gload16(bh0, LB + ldst);
    gload16(bh1, LB + 4096 + ldst);
    gload16(bm0, LB + 8192 + ldst);
    gload16(bm1, LB + 12288 + ldst);

    int parity = 0;
#pragma unroll 2
    for (int kt = 0; kt < EE; kt += 32) {
        uint ahu[8], amu[8];
#pragma unroll
        for (int p = 0; p < 8; p++)
            split2pair(fa[2 * p], fa[2 * p + 1], ahu[p], amu[p]);

        __syncthreads();   // WAR: previous iteration's A-frag reads done
        *(uint4*)(LA +    0 + w0) = make_uint4(ahu[0], ahu[1], ahu[2], ahu[3]);
        *(uint4*)(LA +    0 + w1) = make_uint4(ahu[4], ahu[5], ahu[6], ahu[7]);
        *(uint4*)(LA + 8192 + w0) = make_uint4(amu[0], amu[1], amu[2], amu[3]);
        *(uint4*)(LA + 8192 + w1) = make_uint4(amu[4], amu[5], amu[6], amu[7]);
        __syncthreads();   // A visible; vmcnt(0) drain completes B(kt)

        if (kt + 32 < EE) {
            const int kn = kt + 32;
#pragma unroll
            for (int q = 0; q < 4; q++)
                *(float4*)(fa + q * 4) = *(const float4*)(Aptr + kn + q * 4);
            char* Bn = LB + (parity ^ 1) * 16384;
            gload16(bh0 + kn, Bn + ldst);
            gload16(bh1 + kn, Bn + 4096 + ldst);
            gload16(bm0 + kn, Bn + 8192 + ldst);
            gload16(bm1 + kn, Bn + 12288 + ldst);
        }

        char* const Bb = LB + parity * 16384;
        bf8_t af[4][2];
#pragma unroll
        for (int i = 0; i < 4; i++) {
            const int ro = (arow + i * 16) * 64 + rxor;
            af[i][0] = *(const bf8_t*)(LA +    0 + ro);
            af[i][1] = *(const bf8_t*)(LA + 8192 + ro);
        }
#pragma unroll
        for (int j = 0; j < 4; j++) {
            const int ro = (brow + j * 16) * 64 + rxor;
            bf8_t bh_ = *(const bf8_t*)(Bb +    0 + ro);
            bf8_t bm_ = *(const bf8_t*)(Bb + 8192 + ro);
#pragma unroll
            for (int i = 0; i < 4; i++) {
                f4_t c = acc[i][j];
                c = __builtin_amdgcn_mfma_f32_16x16x32_bf16(af[i][0], bh_, c, 0, 0, 0); // hh
                c = __builtin_amdgcn_mfma_f32_16x16x32_bf16(af[i][0], bm_, c, 0, 0, 0); // hm
                c = __builtin_amdgcn_mfma_f32_16x16x32_bf16(af[i][1], bh_, c, 0, 0, 0); // mh
                acc[i][j] = c;
            }
        }
        parity ^= 1;
    }

#pragma unroll
    for (int j = 0; j < 4; j++) {
        const int n  = n0 + (wave & 1) * 64 + j * 16 + (lane & 15);
        const float bn = bias[n];
        const int h_ = n >> 6, d_ = n & 63;
#pragma unroll
        for (int i = 0; i < 4; i++) {
            const int mb = m0 + (wave >> 1) * 64 + i * 16 + ((lane >> 4) << 2);
#pragma unroll
            for (int r = 0; r < 4; r++) {
                const int m  = mb + r;
                const int b_ = m >> 11;
                const int l_ = m & (LL - 1);
                O[(((size_t)(b_ * HH + h_) * LL + l_) << 6) + d_] = acc[i][j][r] + bn;
            }
        }
    }
}

// ---------------------------------------------------------------------------
// K2a: mean of V stage 1 — 512 blocks = (lchunk 0..15) x (bh 0..31).
// ---------------------------------------------------------------------------
__global__ __launch_bounds__(256) void meanv_part_kernel(const float* __restrict__ v,
                                                         float* __restrict__ vpart)
{
    const int bh    = blockIdx.x & 31;
    const int chunk = blockIdx.x >> 5;
    const int d  = threadIdx.x & 63;
    const int wv = threadIdx.x >> 6;
    const float* base = v + ((size_t)bh * LL + chunk * 128 + wv * 32) * DD + d;
    float acc = 0.0f;
#pragma unroll
    for (int i = 0; i < 32; i++) acc += base[i * DD];
    __shared__ float red[4][DD];
    red[wv][d] = acc;
    __syncthreads();
    if (wv == 0)
        vpart[(size_t)(chunk * 32 + bh) * DD + d]
            = red[0][d] + red[1][d] + red[2][d] + red[3][d];
}

// ---------------------------------------------------------------------------
// K2b: mean of V stage 2 — combine 16 partials per (bh,d).
// ---------------------------------------------------------------------------
__global__ __launch_bounds__(64) void meanv_comb_kernel(const float* __restrict__ vpart,
                                                        float* __restrict__ mean_v)
{
    const int bh = blockIdx.x;
    const int d  = threadIdx.x;
    float s = 0.0f;
#pragma unroll
    for (int c = 0; c < MVC; c++) s += vpart[(size_t)(c * 32 + bh) * DD + d];
    mean_v[bh * DD + d] = s * (1.0f / (float)LL);
}

// ---------------------------------------------------------------------------
// K3: sparsity measure M[b,h,l] = max_s(q.k_sample) - sum_s(q.k_sample)/L
// ---------------------------------------------------------------------------
__global__ __launch_bounds__(256) void measure_kernel(const float* __restrict__ q,
                                                      const float* __restrict__ k,
                                                      const int* __restrict__ idx_sample,
                                                      float* __restrict__ M)
{
    int bh   = blockIdx.x & 31;
    int lc   = blockIdx.x >> 5;
    int lane = threadIdx.x & 63;
    int wv   = threadIdx.x >> 6;
    int l    = lc * 4 + wv;
    int s8   = lane >> 3;   // sample slot 0..7
    int c    = lane & 7;    // d-chunk 0..7

    const float* qrow = q + ((size_t)bh * LL + l) * DD + c * 8;
    float4 q0 = *(const float4*)(qrow);
    float4 q1 = *(const float4*)(qrow + 4);

    const float* kbase = k + (size_t)bh * LL * DD;
    const int*   irow  = idx_sample + l * UU;

    float mx = NEG_INF, sum = 0.0f;
#pragma unroll
    for (int it = 0; it < UU; it += 8) {
        int ki = irow[it + s8];
        const float* krow = kbase + (size_t)ki * DD + c * 8;
        float4 k0 = *(const float4*)(krow);
        float4 k1 = *(const float4*)(krow + 4);
        float p = q0.x*k0.x + q0.y*k0.y + q0.z*k0.z + q0.w*k0.w
                + q1.x*k1.x + q1.y*k1.y + q1.z*k1.z + q1.w*k1.w;
        p += __shfl_xor(p, 1, 64);
        p += __shfl_xor(p, 2, 64);
        p += __shfl_xor(p, 4, 64);
        mx = fmaxf(mx, p);
        sum += p;
    }
    mx  = fmaxf(mx, __shfl_xor(mx, 8, 64));
    sum += __shfl_xor(sum, 8, 64);
    mx  = fmaxf(mx, __shfl_xor(mx, 16, 64));
    sum += __shfl_xor(sum, 16, 64);
    mx  = fmaxf(mx, __shfl_xor(mx, 32, 64));
    sum += __shfl_xor(sum, 32, 64);

    if (lane == 0) M[bh * LL + l] = mx - sum * (1.0f / (float)LL);
}

// ---------------------------------------------------------------------------
// K4: top-40 per (b,h), single-wave register version.
// ---------------------------------------------------------------------------
__global__ __launch_bounds__(64) void topk_kernel(const float* __restrict__ M,
                                                  int* __restrict__ top)
{
    const int bh   = blockIdx.x;
    const int lane = threadIdx.x;

    unsigned long long keys[32];
#pragma unroll
    for (int i = 0; i < 32; i++) {
        int idx = i * 64 + lane;
        uint u  = __float_as_uint(M[bh * LL + idx]);
        uint sv = (u & 0x80000000u) ? ~u : (u | 0x80000000u);
        keys[i] = ((unsigned long long)sv << 32) | (uint)(LL - 1 - idx);
    }
    unsigned long long lmax = 0ull;
#pragma unroll
    for (int i = 0; i < 32; i++) lmax = (keys[i] > lmax) ? keys[i] : lmax;

    for (int it = 0; it < NT; it++) {
        unsigned long long g = lmax;
#pragma unroll
        for (int off = 1; off < 64; off <<= 1) {
            unsigned long long o = __shfl_xor(g, off, 64);
            g = (o > g) ? o : g;
        }
        if (lane == 0) top[bh * NT + it] = LL - 1 - (int)(g & 0xffffffffu);
#pragma unroll
        for (int i = 0; i < 32; i++) if (keys[i] == g) keys[i] = 0ull;
        lmax = 0ull;
#pragma unroll
        for (int i = 0; i < 32; i++) lmax = (keys[i] > lmax) ? keys[i] : lmax;
    }
}

// ---------------------------------------------------------------------------
// K5: flash-style split-K attention partials (R0-measured body).
// ---------------------------------------------------------------------------
__global__ __launch_bounds__(256) void pv_kernel(const float* __restrict__ q,
                                                 const float* __restrict__ k,
                                                 const float* __restrict__ v,
                                                 const int* __restrict__ top,
                                                 float* __restrict__ mpart,
                                                 float* __restrict__ lpart,
                                                 float* __restrict__ accpart)
{
    const int bh    = blockIdx.x & 31;
    const int chunk = blockIdx.x >> 5;
    const int tid   = threadIdx.x;
    const int lane  = tid & 63, wv = tid >> 6;

    __shared__ float qs[NT][DD];        // 10240 B
    __shared__ float sc[NT][CK + 4];    // 10880 B

    for (int i = tid; i < NT * DD / 4; i += 256) {
        int u  = i >> 4;
        int d4 = (i & 15) * 4;
        int l  = top[bh * NT + u];
        *(float4*)&qs[u][d4] = *(const float4*)(q + ((size_t)bh * LL + l) * DD + d4);
    }
    __syncthreads();

    {
        const int key  = tid >> 2;
        const int dseg = tid & 3;
        const float* krow = k + ((size_t)bh * LL + chunk * CK + key) * DD + dseg * 16;
        float4 k0 = *(const float4*)(krow);
        float4 k1 = *(const float4*)(krow + 4);
        float4 k2 = *(const float4*)(krow + 8);
        float4 k3 = *(const float4*)(krow + 12);
#pragma unroll 8
        for (int u = 0; u < NT; u++) {
            const float* qrow = &qs[u][dseg * 16];
            float4 q0 = *(const float4*)(qrow);
            float4 q1 = *(const float4*)(qrow + 4);
            float4 q2 = *(const float4*)(qrow + 8);
            float4 q3 = *(const float4*)(qrow + 12);
            float p = k0.x*q0.x + k0.y*q0.y + k0.z*q0.z + k0.w*q0.w
                    + k1.x*q1.x + k1.y*q1.y + k1.z*q1.z + k1.w*q1.w
                    + k2.x*q2.x + k2.y*q2.y + k2.z*q2.z + k2.w*q2.w
                    + k3.x*q3.x + k3.y*q3.y + k3.z*q3.z + k3.w*q3.w;
            p += __shfl_xor(p, 1, 64);
            p += __shfl_xor(p, 2, 64);
            if (dseg == 0) sc[u][key] = p;
        }
    }
    __syncthreads();

#pragma unroll
    for (int i = 0; i < 10; i++) {
        const int u = wv * 10 + i;
        float val = sc[u][lane];
        float mx = val;
        mx = fmaxf(mx, __shfl_xor(mx, 1, 64));
        mx = fmaxf(mx, __shfl_xor(mx, 2, 64));
        mx = fmaxf(mx, __shfl_xor(mx, 4, 64));
        mx = fmaxf(mx, __shfl_xor(mx, 8, 64));
        mx = fmaxf(mx, __shfl_xor(mx, 16, 64));
        mx = fmaxf(mx, __shfl_xor(mx, 32, 64));
        float e = __expf(val - mx);
        sc[u][lane] = e;
        float s = e;
        s += __shfl_xor(s, 1, 64);
        s += __shfl_xor(s, 2, 64);
        s += __shfl_xor(s, 4, 64);
        s += __shfl_xor(s, 8, 64);
        s += __shfl_xor(s, 16, 64);
        s += __shfl_xor(s, 32, 64);
        if (lane == 0) {
            mpart[(bh * NCH + chunk) * NT + u] = mx;
            lpart[(bh * NCH + chunk) * NT + u] = s;
        }
    }
    __syncthreads();

    {
        float pacc[10];
#pragma unroll
        for (int i = 0; i < 10; i++) pacc[i] = 0.0f;
        const float* vbase = v + ((size_t)bh * LL + chunk * CK) * DD;
#pragma unroll 8
        for (int t = 0; t < CK; t++) {
            float vval = vbase[(size_t)t * DD + lane];
#pragma unroll
            for (int i = 0; i < 10; i++) pacc[i] += sc[wv * 10 + i][t] * vval;
        }
#pragma unroll
        for (int i = 0; i < 10; i++) {
            const int u = wv * 10 + i;
            accpart[(((size_t)(bh * NCH + chunk)) * NT + u) * 64 + lane] = pacc[i];
        }
    }
}

// ---------------------------------------------------------------------------
// K6a: base output row per batch: base[b,e] = meanctx[b,:] . Wo[e,:] + bo[e]
// ---------------------------------------------------------------------------
__global__ __launch_bounds__(256) void base_kernel(const float* __restrict__ mean_v,
                                                   const float* __restrict__ Wo,
                                                   const float* __restrict__ bo,
                                                   float* __restrict__ base)
{
    int lane = threadIdx.x & 63, wv = threadIdx.x >> 6;
    int be = blockIdx.x * 4 + wv;
    int b  = be >> 9;
    int e  = be & (EE - 1);
    const float* mrow = mean_v + b * EE;
    const float* wrow = Wo + (size_t)e * EE;
    float acc = 0.0f;
#pragma unroll
    for (int j = 0; j < 8; j++) acc += mrow[lane + j * 64] * wrow[lane + j * 64];
#pragma unroll
    for (int off = 32; off > 0; off >>= 1) acc += __shfl_down(acc, off, 64);
    if (lane == 0) base[be] = acc + bo[e];
}

// ---------------------------------------------------------------------------
// K6b: broadcast base row to all l
// ---------------------------------------------------------------------------
__global__ __launch_bounds__(256) void bcast_kernel(const float* __restrict__ base,
                                                    float* __restrict__ out)
{
    size_t fi = ((size_t)blockIdx.x * 256 + threadIdx.x) * 4;
    int b  = (int)(fi >> 20);
    int e4 = (int)(fi & (EE - 1));
    float4 val = *(const float4*)(base + b * EE + e4);
    *(float4*)(out + fi) = val;
}

// ---------------------------------------------------------------------------
// K6c-1: delta precompute — SPLIT OUT of corr (R3 post-mortem: corr was a
// 56us pure-latency kernel; phase 1's 10-sequential-u x 32-chunk loops on
// 128 blocks ~= 33us of exposed latency at 5% occupancy). One block per
// (bh,u): 1280 blocks x 64 threads -> every u's 32-chunk reduction runs in
// parallel. Accumulation order identical to R2/R3 (bit-identical delta).
// ---------------------------------------------------------------------------
__global__ __launch_bounds__(64) void delta_kernel(const float* __restrict__ accpart,
                                                   const float* __restrict__ lpart,
                                                   const float* __restrict__ mpart,
                                                   const float* __restrict__ mean_v,
                                                   float* __restrict__ delta_ws)
{
    const int bhu = blockIdx.x;
    const int bh  = bhu / NT;
    const int u   = bhu % NT;
    const int d   = threadIdx.x;

    const float* mp = mpart + (size_t)bh * NCH * NT + u;
    const float* lp = lpart + (size_t)bh * NCH * NT + u;
    const float* ap = accpart + ((size_t)bh * NCH * NT + u) * 64 + d;

    float m = NEG_INF;
#pragma unroll
    for (int c = 0; c < NCH; c++) m = fmaxf(m, mp[c * NT]);
    float den = 0.0f, num = 0.0f;
#pragma unroll
    for (int c = 0; c < NCH; c++) {
        float f = __expf(mp[c * NT] - m);
        den += lp[c * NT] * f;
        num += ap[(size_t)c * NT * 64] * f;
    }
    delta_ws[(size_t)bhu * 64 + d] = num / den - mean_v[bh * DD + d];
}

// ---------------------------------------------------------------------------
// K6c-2: correction GEMV + scatter. 256 blocks = (ec 0..7) x (bh 0..31),
// 256 threads. Wave = u-decade, lane = e-offset:
//  - delta rows from LDS as wave-uniform ds_read_b128 broadcasts (160/wave,
//    conflict-free) instead of 2560 scalar reads/thread.
//  - Wo row (64 f32) register-cached per lane (one-time 16KB/block from L2).
//  - atomicAdd per u is a 64-lane consecutive-e coalesced line.
// Dot accumulates d-ascending via fmaf chain — same rounding as R2/R3.
// ---------------------------------------------------------------------------
__global__ __launch_bounds__(256) void corr2_kernel(const float* __restrict__ delta_ws,
                                                    const int* __restrict__ top,
                                                    const float* __restrict__ Wo,
                                                    float* __restrict__ out)
{
    const int bh  = blockIdx.x & 31;
    const int ec  = blockIdx.x >> 5;     // 0..7
    const int h   = bh & (HH - 1);
    const int b   = bh >> 3;
    const int tid = threadIdx.x;
    const int lane = tid & 63;
    const int wv   = tid >> 6;

    __shared__ alignas(16) float dl[NT][DD];   // 10240 B, b128-aligned rows
    __shared__ int ltab[NT];

    // stage delta[bh] coalesced (640 float4)
    for (int i = tid; i < NT * DD / 4; i += 256) {
        const int u  = i >> 4;
        const int d4 = (i & 15) * 4;
        *(float4*)&dl[u][d4] = *(const float4*)(delta_ws + ((size_t)(bh * NT + u)) * 64 + d4);
    }
    if (tid < NT) ltab[tid] = top[bh * NT + tid];

    // register-cache this lane's Wo row: e = ec*64 + lane, d = h*64..h*64+63
    const int e = ec * 64 + lane;
    const float* wrow = Wo + (size_t)e * EE + h * DD;
    float4 wo[16];
#pragma unroll
    for (int j = 0; j < 16; j++) wo[j] = *(const float4*)(wrow + j * 4);

    __syncthreads();

    float* obase = out + (size_t)b * LL * EE + e;
#pragma unroll
    for (int uu = 0; uu < 10; uu++) {
        const int u = wv * 10 + uu;
        float acc = 0.0f;
#pragma unroll
        for (int j = 0; j < 16; j++) {
            float4 dv = *(const float4*)&dl[u][j * 4];   // wave-uniform broadcast
            acc = fmaf(dv.x, wo[j].x, acc);
            acc = fmaf(dv.y, wo[j].y, acc);
            acc = fmaf(dv.z, wo[j].z, acc);
            acc = fmaf(dv.w, wo[j].w, acc);
        }
        atomicAdd(obase + (size_t)ltab[u] * EE, acc);    // 64-lane coalesced
    }
}

// ---------------------------------------------------------------------------
extern "C" void kernel_launch(void* const* d_in, const int* in_sizes, int n_in,
                              void* d_out, int out_size, void* d_ws, size_t ws_size,
                              hipStream_t stream)
{
    const float* query = (const float*)d_in[0];
    const float* key   = (const float*)d_in[1];
    const float* value = (const float*)d_in[2];
    const int*   idxs  = (const int*)d_in[3];
    const float* Wq = (const float*)d_in[4];
    const float* bq = (const float*)d_in[5];
    const float* Wk = (const float*)d_in[6];
    const float* bk = (const float*)d_in[7];
    const float* Wv = (const float*)d_in[8];
    const float* bv = (const float*)d_in[9];
    const float* Wo = (const float*)d_in[10];
    const float* bo = (const float*)d_in[11];
    float* out = (float*)d_out;

    // workspace layout (~60 MB)
    char* ws = (char*)d_ws;
    size_t off = 0;
    const size_t qkv_bytes = (size_t)BB * HH * LL * DD * sizeof(float); // 16 MB each
    float* q_ws = (float*)(ws + off); off += qkv_bytes;
    float* k_ws = (float*)(ws + off); off += qkv_bytes;
    float* v_ws = (float*)(ws + off); off += qkv_bytes;
    float* M_ws    = (float*)(ws + off); off += (size_t)BB * HH * LL * sizeof(float);
    int*   top_ws  = (int*)(ws + off);   off += (size_t)BB * HH * NT * sizeof(int);
    float* mean_ws = (float*)(ws + off); off += (size_t)BB * HH * DD * sizeof(float);
    float* vpart_ws = (float*)(ws + off); off += (size_t)BB * HH * MVC * DD * sizeof(float);
    float* mpart_ws = (float*)(ws + off); off += (size_t)BB * HH * NCH * NT * sizeof(float);
    float* lpart_ws = (float*)(ws + off); off += (size_t)BB * HH * NCH * NT * sizeof(float);
    float* accpart_ws = (float*)(ws + off); off += (size_t)BB * HH * NCH * NT * DD * sizeof(float);
    float* base_ws = (float*)(ws + off); off += (size_t)BB * EE * sizeof(float);
    float* delta_ws = (float*)(ws + off); off += (size_t)BB * HH * NT * DD * sizeof(float); // 320KB

    // Converted-W planes (3 MB) alias the head of accpart_ws (lifetimes
    // disjoint: wconv->proj vs pv->delta).
    unsigned short* wcv_ws = (unsigned short*)accpart_ws;

    // K0: pre-convert W to bf16 hi+mid planes
    wconv_kernel<<<384, 256, 0, stream>>>(Wq, Wk, Wv, wcv_ws);
    // K1: QKV projections (split-bf16 MFMA, 3 products, gload_lds B, prefetch)
    proj_kernel<<<768, 256, 0, stream>>>(query, key, value, wcv_ws, bq, bk, bv,
                                         q_ws, k_ws, v_ws);
    // K2: mean of V (two-stage)
    meanv_part_kernel<<<BB * HH * MVC, 256, 0, stream>>>(v_ws, vpart_ws);
    meanv_comb_kernel<<<BB * HH, 64, 0, stream>>>(vpart_ws, mean_ws);
    // K3: sparsity measure
    measure_kernel<<<(LL / 4) * 32, 256, 0, stream>>>(q_ws, k_ws, idxs, M_ws);
    // K4: top-40 (single wave per bh)
    topk_kernel<<<BB * HH, 64, 0, stream>>>(M_ws, top_ws);
    // K5: split-K attention partials
    pv_kernel<<<BB * HH * NCH, 256, 0, stream>>>(q_ws, k_ws, v_ws, top_ws,
                                                 mpart_ws, lpart_ws, accpart_ws);
    // K6: output projection (base + broadcast + delta + combine/correct)
    base_kernel<<<(BB * EE) / 4, 256, 0, stream>>>(mean_ws, Wo, bo, base_ws);
    bcast_kernel<<<(BB * LL * EE) / (256 * 4), 256, 0, stream>>>(base_ws, out);
    delta_kernel<<<BB * HH * NT, 64, 0, stream>>>(accpart_ws, lpart_ws, mpart_ws,
                                                  mean_ws, delta_ws);
    corr2_kernel<<<256, 256, 0, stream>>>(delta_ws, top_ws, Wo, out);
}